// Round 1
// baseline (76.181 us; speedup 1.0000x reference)
//
#include <hip/hip_runtime.h>
#include <math.h>

#define D_FEAT 256
#define NROW   4096
#define PPAIR  2048
#define TILE   64
#define KCH    16
#define LDA    68   // padded leading dim for LDS (float4-aligned, 2-way max aliasing)

// ws layout (floats): Spart[2*8][2048] then Jsq[2048]

__global__ __launch_bounds__(256) void sml_gemm_exp_rowsum(
    const float* __restrict__ X, float* __restrict__ Spart)
{
    __shared__ float A_s[KCH][LDA];
    __shared__ float B_s[KCH][LDA];

    const int rt   = blockIdx.x;   // 0..31 row tile
    const int cg   = blockIdx.y;   // 0..7  column group (4 tiles of 64 each)
    const int gemm = blockIdx.z;   // 0: Rodd (A=even rows,B=odd rows); 1: Reven

    const int t  = threadIdx.x;
    const int tx = t & 15;
    const int ty = t >> 4;

    const int p0 = rt * TILE;

    // staging mapping: each thread loads one float4 per tile-chunk
    const int sr  = t >> 2;       // 0..63: tile row/col index
    const int sd0 = (t & 3) * 4;  // 0,4,8,12 within the 16-wide K chunk

    const int arow = 2 * (p0 + sr) + gemm;

    float row_acc[4] = {0.f, 0.f, 0.f, 0.f};

    for (int ct = 0; ct < 4; ++ct) {
        const int k0   = cg * 256 + ct * TILE;
        const int brow = 2 * (k0 + sr) + (1 - gemm);

        float acc[4][4];
        #pragma unroll
        for (int i = 0; i < 4; ++i)
            #pragma unroll
            for (int j = 0; j < 4; ++j) acc[i][j] = 0.f;

        // prefetch first chunk
        float4 av = *reinterpret_cast<const float4*>(&X[arow * D_FEAT + sd0]);
        float4 bv = *reinterpret_cast<const float4*>(&X[brow * D_FEAT + sd0]);

        for (int d0 = 0; d0 < D_FEAT; d0 += KCH) {
            __syncthreads();   // previous chunk's LDS reads done
            A_s[sd0 + 0][sr] = av.x; A_s[sd0 + 1][sr] = av.y;
            A_s[sd0 + 2][sr] = av.z; A_s[sd0 + 3][sr] = av.w;
            B_s[sd0 + 0][sr] = bv.x; B_s[sd0 + 1][sr] = bv.y;
            B_s[sd0 + 2][sr] = bv.z; B_s[sd0 + 3][sr] = bv.w;
            __syncthreads();
            if (d0 + KCH < D_FEAT) {   // prefetch next chunk during compute
                av = *reinterpret_cast<const float4*>(&X[arow * D_FEAT + d0 + KCH + sd0]);
                bv = *reinterpret_cast<const float4*>(&X[brow * D_FEAT + d0 + KCH + sd0]);
            }
            #pragma unroll
            for (int dd = 0; dd < KCH; ++dd) {
                const float4 a4 = *reinterpret_cast<const float4*>(&A_s[dd][ty * 4]);
                const float4 b4 = *reinterpret_cast<const float4*>(&B_s[dd][tx * 4]);
                const float a[4] = {a4.x, a4.y, a4.z, a4.w};
                const float b[4] = {b4.x, b4.y, b4.z, b4.w};
                #pragma unroll
                for (int i = 0; i < 4; ++i)
                    #pragma unroll
                    for (int j = 0; j < 4; ++j)
                        acc[i][j] = fmaf(a[i], b[j], acc[i][j]);
            }
        }

        // epilogue: exp(1 + d/128), mask excluded element, row-sum this 64-col tile
        #pragma unroll
        for (int i = 0; i < 4; ++i) {
            const int p    = p0 + ty * 4 + i;
            const int excl = (gemm == 0) ? (2 * p + 1) : (2 * p);
            float part = 0.f;
            #pragma unroll
            for (int j = 0; j < 4; ++j) {
                const int k = k0 + tx * 4 + j;
                float e = __expf(1.0f + acc[i][j] * (1.0f / 128.0f));
                if (k == excl) e = 0.f;
                part += e;
            }
            part += __shfl_xor(part, 1);
            part += __shfl_xor(part, 2);
            part += __shfl_xor(part, 4);
            part += __shfl_xor(part, 8);
            row_acc[i] += part;   // valid on tx==0 lanes
        }
    }

    if (tx == 0) {
        #pragma unroll
        for (int i = 0; i < 4; ++i) {
            const int p = p0 + ty * 4 + i;
            Spart[(gemm * 8 + cg) * PPAIR + p] = row_acc[i];
        }
    }
}

__global__ __launch_bounds__(256) void sml_finish_pairs(
    const float* __restrict__ X, const float* __restrict__ Spart,
    float* __restrict__ Jsq)
{
    const int t    = threadIdx.x;
    const int wave = t >> 6;
    const int lane = t & 63;
    const int p    = blockIdx.x * 4 + wave;   // 512 blocks x 4 waves = 2048 pairs

    const float4 a = *reinterpret_cast<const float4*>(&X[(2 * p)     * D_FEAT + lane * 4]);
    const float4 b = *reinterpret_cast<const float4*>(&X[(2 * p + 1) * D_FEAT + lane * 4]);
    float dp = a.x * b.x + a.y * b.y + a.z * b.z + a.w * b.w;
    #pragma unroll
    for (int m = 1; m < 64; m <<= 1) dp += __shfl_xor(dp, m);

    if (lane == 0) {
        float s = 0.f;
        #pragma unroll
        for (int g = 0; g < 16; ++g) s += Spart[g * PPAIR + p];
        const float J = __logf(1e-8f + s) - dp * (1.0f / 128.0f);
        const float v = fmaxf(J, 0.f);
        Jsq[p] = v * v;
    }
}

__global__ __launch_bounds__(256) void sml_final_reduce(
    const float* __restrict__ Jsq, float* __restrict__ out)
{
    __shared__ float red[4];
    const int t = threadIdx.x;
    float s = 0.f;
    #pragma unroll
    for (int i = 0; i < PPAIR / 256; ++i) s += Jsq[t + 256 * i];
    #pragma unroll
    for (int m = 1; m < 64; m <<= 1) s += __shfl_xor(s, m);
    if ((t & 63) == 0) red[t >> 6] = s;
    __syncthreads();
    if (t == 0) out[0] = (red[0] + red[1] + red[2] + red[3]) * (1.0f / 4096.0f);
}

extern "C" void kernel_launch(void* const* d_in, const int* in_sizes, int n_in,
                              void* d_out, int out_size, void* d_ws, size_t ws_size,
                              hipStream_t stream) {
    const float* X = (const float*)d_in[0];
    float* ws    = (float*)d_ws;
    float* Spart = ws;                  // 16 * 2048 floats
    float* Jsq   = ws + 16 * PPAIR;     // 2048 floats
    float* out   = (float*)d_out;

    dim3 g1(32, 8, 2);
    sml_gemm_exp_rowsum<<<g1, dim3(256), 0, stream>>>(X, Spart);
    sml_finish_pairs<<<512, 256, 0, stream>>>(X, Spart, Jsq);
    sml_final_reduce<<<1, 256, 0, stream>>>(Jsq, out);
}

// Round 3
// 21.405 us; speedup vs baseline: 3.5590x; 3.5590x over previous
//
#include <hip/hip_runtime.h>
#include <hip/hip_bf16.h>

#define PN 2048

typedef __attribute__((ext_vector_type(8))) short short8;
typedef __attribute__((ext_vector_type(4))) float f32x4;

static __device__ __forceinline__ unsigned int pk_bf2(float lo, float hi) {
    unsigned int ul = __float_as_uint(lo);
    unsigned int uh = __float_as_uint(hi);
    ul = (ul + 0x7fffu + ((ul >> 16) & 1u)) >> 16;   // RNE f32->bf16
    uh = (uh + 0x7fffu + ((uh >> 16) & 1u)) >> 16;
    return ul | (uh << 16);
}

// ws layout (floats): Spart[2*16][2048] (written once per (gemm,colblock,row)), Dpos[2048]

__global__ __launch_bounds__(256, 2) void sml_mfma(
    const float* __restrict__ X, float* __restrict__ Spart, float* __restrict__ Dpos)
{
    __shared__ __align__(16) unsigned int A_s[128 * 32];  // [row][32 uints] = bf16[row][64], 16B-slot XOR-swizzled
    __shared__ __align__(16) unsigned int B_s[128 * 32];
    __shared__ float S_red[2][128];

    const int bx = blockIdx.x, by = blockIdx.y, gemm = blockIdx.z;
    const int t = threadIdx.x;
    const int lane = t & 63, wid = t >> 6;
    const int wr = wid >> 1, wc = wid & 1;

    // staging: thread handles k-slot s of rows r0+32q (q=0..3), for both A and B
    const int s  = t & 7;
    const int r0 = t >> 3;

    const float* aptr[4];
    const float* bptr[4];
    #pragma unroll
    for (int q = 0; q < 4; ++q) {
        const int r = r0 + 32 * q;
        aptr[q] = X + (size_t)(2 * (bx * 128 + r) + gemm) * 256 + s * 8;
        bptr[q] = X + (size_t)(2 * (by * 128 + r) + (1 - gemm)) * 256 + s * 8;
    }

    f32x4 acc[4][4];
    #pragma unroll
    for (int i = 0; i < 4; ++i)
        #pragma unroll
        for (int j = 0; j < 4; ++j) acc[i][j] = (f32x4){0.f, 0.f, 0.f, 0.f};

    float4 pa[4][2], pb[4][2];
    #pragma unroll
    for (int q = 0; q < 4; ++q) {
        pa[q][0] = *(const float4*)(aptr[q] + 0);
        pa[q][1] = *(const float4*)(aptr[q] + 4);
        pb[q][0] = *(const float4*)(bptr[q] + 0);
        pb[q][1] = *(const float4*)(bptr[q] + 4);
    }

    const int g4 = lane >> 4;   // k-group 0..3
    const int rl = lane & 15;

    for (int ks = 0; ks < 4; ++ks) {
        __syncthreads();   // previous chunk's LDS reads done
        #pragma unroll
        for (int q = 0; q < 4; ++q) {
            const int r  = r0 + 32 * q;
            const int sw = (s ^ (r & 7)) << 2;
            uint4 wa = { pk_bf2(pa[q][0].x, pa[q][0].y), pk_bf2(pa[q][0].z, pa[q][0].w),
                         pk_bf2(pa[q][1].x, pa[q][1].y), pk_bf2(pa[q][1].z, pa[q][1].w) };
            uint4 wb = { pk_bf2(pb[q][0].x, pb[q][0].y), pk_bf2(pb[q][0].z, pb[q][0].w),
                         pk_bf2(pb[q][1].x, pb[q][1].y), pk_bf2(pb[q][1].z, pb[q][1].w) };
            *(uint4*)&A_s[r * 32 + sw] = wa;
            *(uint4*)&B_s[r * 32 + sw] = wb;
        }
        __syncthreads();
        if (ks < 3) {   // prefetch next chunk's fp32 into regs; consumed after next barrier
            const int off = (ks + 1) * 64;
            #pragma unroll
            for (int q = 0; q < 4; ++q) {
                pa[q][0] = *(const float4*)(aptr[q] + off);
                pa[q][1] = *(const float4*)(aptr[q] + off + 4);
                pb[q][0] = *(const float4*)(bptr[q] + off);
                pb[q][1] = *(const float4*)(bptr[q] + off + 4);
            }
        }
        #pragma unroll
        for (int kk = 0; kk < 2; ++kk) {
            short8 af[4], bfj[4];
            #pragma unroll
            for (int i = 0; i < 4; ++i) {
                const int r  = wr * 64 + i * 16 + rl;
                const int sl = (kk * 4 + g4) ^ (r & 7);
                af[i] = *(const short8*)&A_s[r * 32 + sl * 4];
            }
            #pragma unroll
            for (int j = 0; j < 4; ++j) {
                const int r  = wc * 64 + j * 16 + rl;
                const int sl = (kk * 4 + g4) ^ (r & 7);
                bfj[j] = *(const short8*)&B_s[r * 32 + sl * 4];
            }
            #pragma unroll
            for (int i = 0; i < 4; ++i)
                #pragma unroll
                for (int j = 0; j < 4; ++j)
                    acc[i][j] = __builtin_amdgcn_mfma_f32_16x16x32_bf16(af[i], bfj[j], acc[i][j], 0, 0, 0);
        }
    }

    // fused epilogue: exp(1 + c/128), mask k==excl, extract Dpos (gemm 0 diagonal), row-reduce
    const int prow_base = bx * 128 + wr * 64;
    const int kcol_base = by * 128 + wc * 64;
    float rs[4][4];
    #pragma unroll
    for (int i = 0; i < 4; ++i)
        #pragma unroll
        for (int rg = 0; rg < 4; ++rg) rs[i][rg] = 0.f;

    #pragma unroll
    for (int i = 0; i < 4; ++i) {
        #pragma unroll
        for (int j = 0; j < 4; ++j) {
            const int k = kcol_base + j * 16 + rl;       // C/D: col = lane&15 [m89]
            #pragma unroll
            for (int rg = 0; rg < 4; ++rg) {
                const int p = prow_base + i * 16 + g4 * 4 + rg;   // row = (lane>>4)*4 + reg
                const float c = acc[i][j][rg] * (1.f / 128.f);
                if (gemm == 0 && k == p) Dpos[p] = c;             // D[2p,2p+1]
                float e = __expf(1.f + c);
                const int excl = (gemm == 0) ? (2 * p + 1) : (2 * p);
                if (k == excl) e = 0.f;
                rs[i][rg] += e;
            }
        }
    }
    #pragma unroll
    for (int i = 0; i < 4; ++i) {
        #pragma unroll
        for (int rg = 0; rg < 4; ++rg) {
            float v = rs[i][rg];
            v += __shfl_xor(v, 1); v += __shfl_xor(v, 2);
            v += __shfl_xor(v, 4); v += __shfl_xor(v, 8);
            if (rl == 0) S_red[wc][wr * 64 + i * 16 + g4 * 4 + rg] = v;
        }
    }
    __syncthreads();
    if (t < 128)
        Spart[(gemm * 16 + by) * PN + bx * 128 + t] = S_red[0][t] + S_red[1][t];
}

__global__ __launch_bounds__(1024) void sml_finish(
    const float* __restrict__ Spart, const float* __restrict__ Dpos, float* __restrict__ out)
{
    __shared__ float red[16];
    const int t = threadIdx.x;
    float local = 0.f;
    for (int p = t; p < PN; p += 1024) {
        float ssum = 0.f;
        #pragma unroll
        for (int g = 0; g < 32; ++g) ssum += Spart[g * PN + p];
        const float J = __logf(1e-8f + ssum) - Dpos[p];
        const float v = fmaxf(J, 0.f);
        local += v * v;
    }
    #pragma unroll
    for (int m = 1; m < 64; m <<= 1) local += __shfl_xor(local, m);
    if ((t & 63) == 0) red[t >> 6] = local;
    __syncthreads();
    if (t == 0) {
        float ssum = 0.f;
        #pragma unroll
        for (int w = 0; w < 16; ++w) ssum += red[w];
        out[0] = ssum * (1.f / 4096.f);
    }
}

extern "C" void kernel_launch(void* const* d_in, const int* in_sizes, int n_in,
                              void* d_out, int out_size, void* d_ws, size_t ws_size,
                              hipStream_t stream) {
    const float* X = (const float*)d_in[0];
    float* ws    = (float*)d_ws;
    float* Spart = ws;                 // 32 * 2048 floats
    float* Dpos  = ws + 32 * PN;       // 2048 floats
    float* out   = (float*)d_out;

    dim3 g1(16, 16, 2);
    sml_mfma<<<g1, dim3(256), 0, stream>>>(X, Spart, Dpos);
    sml_finish<<<1, dim3(1024), 0, stream>>>(Spart, Dpos, out);
}